// Round 6
// baseline (403.461 us; speedup 1.0000x reference)
//
#include <hip/hip_runtime.h>
#include <hip/hip_bf16.h>

#define B_SZ 512
#define I_SZ 7
#define D_SZ 512
#define J_SZ 64
#define E_SZ 128
#define N_SZ 8192
#define ITERS 10

typedef __attribute__((ext_vector_type(8))) short bf16x8;
typedef __attribute__((ext_vector_type(4))) float f32x4;

#define LST 40   // LDS row stride in shorts (32 k + 8 pad): 16B-aligned, <=2-way banks

#if defined(__has_builtin)
#if __has_builtin(__builtin_amdgcn_cvt_pk_bf16_f32)
#define HAVE_CVT_PK_BF16 1
#endif
#endif

// Split a PAIR of fp32 into packed-bf16 hi and lo words (RNE both stages).
__device__ inline void split2(float x0, float x1, unsigned& hp, unsigned& lp) {
#ifdef HAVE_CVT_PK_BF16
    auto h = __builtin_amdgcn_cvt_pk_bf16_f32(x0, x1);
    hp = __builtin_bit_cast(unsigned, h);
    union { unsigned u; float f; } b0, b1;
    b0.u = hp << 16;
    b1.u = hp & 0xFFFF0000u;
    auto l = __builtin_amdgcn_cvt_pk_bf16_f32(x0 - b0.f, x1 - b1.f);
    lp = __builtin_bit_cast(unsigned, l);
#else
    union { float f; unsigned u; } u0, u1;
    u0.f = x0; u1.f = x1;
    unsigned r0 = u0.u + 0x7FFF + ((u0.u >> 16) & 1);
    unsigned r1 = u1.u + 0x7FFF + ((u1.u >> 16) & 1);
    hp = __builtin_amdgcn_perm(r1, r0, 0x07060302);
    union { unsigned u; float f; } h0, h1;
    h0.u = r0 & 0xFFFF0000u;
    h1.u = r1 & 0xFFFF0000u;
    union { float f; unsigned u; } s0, s1;
    s0.f = x0 - h0.f; s1.f = x1 - h1.f;
    unsigned q0 = s0.u + 0x7FFF + ((s0.u >> 16) & 1);
    unsigned q1 = s1.u + 0x7FFF + ((s1.u >> 16) & 1);
    lp = __builtin_amdgcn_perm(q1, q0, 0x07060302);
#endif
}

// ---------------------------------------------------------------------------
// Kernel 1: vote GEMM via bf16 MFMA, 3-pass hi/lo split.
// R6: 128x256 block, 64x128 WAVE tile (4x8 MFMA tiles of 16x16x32, acc=128
// VGPR). 2x MACs per staged LDS byte vs R5 -> DS pipe drops below MFMA pipe.
// 256 threads = 4 waves: wr=wave&1 (m half), wc=wave>>1 (n half of 128).
// acc += Ahi*Bhi + Ahi*Blo + Alo*Bhi  (lo*lo dropped, ~2^-18 rel).
// ---------------------------------------------------------------------------
__global__ __launch_bounds__(256) void vote_gemm_mfma(
    const float* __restrict__ f,   // [B, I, D]
    const float* __restrict__ W,   // [I, D, N]
    float* __restrict__ fW)        // [B, I, N]
{
    const int i  = blockIdx.z;
    const int m0 = blockIdx.y * 128;
    const int n0 = blockIdx.x * 256;
    const int th = threadIdx.x;

    __shared__ short As_hi[128 * LST], As_lo[128 * LST];  // [m][k]
    __shared__ short Bs_hi[256 * LST], Bs_lo[256 * LST];  // [n][k] (transposed)

    // A staging: thread -> (row m, k-half of 16); 16 values
    const int am  = th >> 1;
    const int akg = th & 1;
    // B staging: thread -> one n column, all 32 k; 32 values
    const int bn  = th;

    const float* fA = f + (size_t)(m0 + am) * (I_SZ * D_SZ) + (size_t)i * D_SZ + akg * 16;
    const float* WB = W + (size_t)i * D_SZ * N_SZ + n0 + bn;

    const int wave = th >> 6, lane = th & 63;
    const int wr = wave & 1, wc = wave >> 1;
    const int lm = lane & 15, quad = lane >> 4;

    f32x4 acc[4][8];
#pragma unroll
    for (int a = 0; a < 4; ++a)
#pragma unroll
        for (int c = 0; c < 8; ++c)
            acc[a][c] = (f32x4){0.f, 0.f, 0.f, 0.f};

    for (int k0 = 0; k0 < D_SZ; k0 += 32) {
        // ---- global loads ----
        float av[16];
        {
            const float* pa = fA + k0;
            float4 t0 = *(const float4*)(pa);
            float4 t1 = *(const float4*)(pa + 4);
            float4 t2 = *(const float4*)(pa + 8);
            float4 t3 = *(const float4*)(pa + 12);
            av[0]=t0.x; av[1]=t0.y; av[2]=t0.z; av[3]=t0.w;
            av[4]=t1.x; av[5]=t1.y; av[6]=t1.z; av[7]=t1.w;
            av[8]=t2.x; av[9]=t2.y; av[10]=t2.z; av[11]=t2.w;
            av[12]=t3.x; av[13]=t3.y; av[14]=t3.z; av[15]=t3.w;
        }
        float bv[32];
        {
            const float* pb = WB + (size_t)k0 * N_SZ;
#pragma unroll
            for (int r = 0; r < 32; ++r) bv[r] = pb[(size_t)r * N_SZ];
        }

        // ---- pair-split ----
        unsigned ahw[8], alw[8];
#pragma unroll
        for (int r = 0; r < 8; ++r) split2(av[2 * r], av[2 * r + 1], ahw[r], alw[r]);
        unsigned bhw[16], blw[16];
#pragma unroll
        for (int r = 0; r < 16; ++r) split2(bv[2 * r], bv[2 * r + 1], bhw[r], blw[r]);

        __syncthreads();   // previous tile's frag reads complete
        *(uint4*)&As_hi[am * LST + akg * 16]     = make_uint4(ahw[0], ahw[1], ahw[2], ahw[3]);
        *(uint4*)&As_hi[am * LST + akg * 16 + 8] = make_uint4(ahw[4], ahw[5], ahw[6], ahw[7]);
        *(uint4*)&As_lo[am * LST + akg * 16]     = make_uint4(alw[0], alw[1], alw[2], alw[3]);
        *(uint4*)&As_lo[am * LST + akg * 16 + 8] = make_uint4(alw[4], alw[5], alw[6], alw[7]);
#pragma unroll
        for (int s = 0; s < 4; ++s) {
            *(uint4*)&Bs_hi[bn * LST + s * 8] =
                make_uint4(bhw[4 * s], bhw[4 * s + 1], bhw[4 * s + 2], bhw[4 * s + 3]);
            *(uint4*)&Bs_lo[bn * LST + s * 8] =
                make_uint4(blw[4 * s], blw[4 * s + 1], blw[4 * s + 2], blw[4 * s + 3]);
        }
        __syncthreads();   // staging visible

        // ---- fragment loads + MFMA (4 m-tiles x 8 n-tiles) ----
        bf16x8 Ah[4], Al[4];
#pragma unroll
        for (int t = 0; t < 4; ++t) {
            const int ar = (wr * 64 + t * 16 + lm) * LST + quad * 8;
            Ah[t] = *(const bf16x8*)&As_hi[ar];
            Al[t] = *(const bf16x8*)&As_lo[ar];
        }
        bf16x8 Bh[8], Bl[8];
#pragma unroll
        for (int u = 0; u < 8; ++u) {
            const int br = (wc * 128 + u * 16 + lm) * LST + quad * 8;
            Bh[u] = *(const bf16x8*)&Bs_hi[br];
            Bl[u] = *(const bf16x8*)&Bs_lo[br];
        }
#pragma unroll
        for (int tm = 0; tm < 4; ++tm)
#pragma unroll
            for (int tn = 0; tn < 8; ++tn) {
                acc[tm][tn] = __builtin_amdgcn_mfma_f32_16x16x32_bf16(Ah[tm], Bh[tn], acc[tm][tn], 0, 0, 0);
                acc[tm][tn] = __builtin_amdgcn_mfma_f32_16x16x32_bf16(Ah[tm], Bl[tn], acc[tm][tn], 0, 0, 0);
                acc[tm][tn] = __builtin_amdgcn_mfma_f32_16x16x32_bf16(Al[tm], Bh[tn], acc[tm][tn], 0, 0, 0);
            }
    }

    // ---- write C: D layout col=lane&15, row=quad*4+reg ----
#pragma unroll
    for (int tm = 0; tm < 4; ++tm) {
        const int rowb = m0 + wr * 64 + tm * 16 + quad * 4;
#pragma unroll
        for (int tn = 0; tn < 8; ++tn) {
            const int col = n0 + wc * 128 + tn * 16 + lm;
#pragma unroll
            for (int r = 0; r < 4; ++r)
                fW[((size_t)(rowb + r) * I_SZ + i) * N_SZ + col] = acc[tm][tn][r];
        }
    }
}

// ---------------------------------------------------------------------------
// Kernel 2: routing via Gram matrices (unchanged — see R4 notes).
// ---------------------------------------------------------------------------
__global__ __launch_bounds__(1024) void routing_kernel(
    const float* __restrict__ fW,  // [B, I, N]
    const float* __restrict__ p,   // [B, I]
    float* __restrict__ c_out,     // [B, J, E]
    float* __restrict__ r_out)     // [B, I, J]
{
    const int b   = blockIdx.x;
    const int tid = threadIdx.x;
    const int j   = tid >> 4;
    const int sub = tid & 15;

    __shared__ float G_sh[64][49];
    __shared__ float s_sh[64][9];
    __shared__ float w_sh[2][64][9];
    __shared__ float p_sh[8];

    if (tid < I_SZ) p_sh[tid] = p[(size_t)b * I_SZ + tid];

    float4 fw[I_SZ][2];
    const float* base = fW + (size_t)b * I_SZ * N_SZ + j * E_SZ + sub * 8;
#pragma unroll
    for (int i = 0; i < I_SZ; ++i) {
        fw[i][0] = *(const float4*)(base + (size_t)i * N_SZ);
        fw[i][1] = *(const float4*)(base + (size_t)i * N_SZ + 4);
    }

#pragma unroll
    for (int i = 0; i < I_SZ; ++i) {
        float s = fw[i][0].x + fw[i][0].y + fw[i][0].z + fw[i][0].w
                + fw[i][1].x + fw[i][1].y + fw[i][1].z + fw[i][1].w;
        s += __shfl_xor(s, 1); s += __shfl_xor(s, 2);
        s += __shfl_xor(s, 4); s += __shfl_xor(s, 8);
        if (sub == 0) s_sh[j][i] = s;
#pragma unroll
        for (int i2 = i; i2 < I_SZ; ++i2) {
            float g = fw[i][0].x * fw[i2][0].x + fw[i][0].y * fw[i2][0].y
                    + fw[i][0].z * fw[i2][0].z + fw[i][0].w * fw[i2][0].w
                    + fw[i][1].x * fw[i2][1].x + fw[i][1].y * fw[i2][1].y
                    + fw[i][1].z * fw[i2][1].z + fw[i][1].w * fw[i2][1].w;
            g += __shfl_xor(g, 1); g += __shfl_xor(g, 2);
            g += __shfl_xor(g, 4); g += __shfl_xor(g, 8);
            if (sub == 0) { G_sh[j][i * 7 + i2] = g; G_sh[j][i2 * 7 + i] = g; }
        }
    }
    __syncthreads();

    for (int t = 0; t < ITERS; ++t) {
        if (tid < I_SZ * 64) {
            const int ii = tid >> 6;
            const int jj = tid & 63;
            float l;
            if (t == 0) {
                l = s_sh[jj][ii];
            } else {
                const int rb = t & 1;
                l = 0.f;
#pragma unroll
                for (int i2 = 0; i2 < I_SZ; ++i2)
                    l = fmaf(w_sh[rb][jj][i2], G_sh[jj][ii * 7 + i2], l);
            }
            float mx = l;
#pragma unroll
            for (int off = 32; off > 0; off >>= 1)
                mx = fmaxf(mx, __shfl_xor(mx, off));
            float ex = __expf(l - mx);
            float sm = ex;
#pragma unroll
            for (int off = 32; off > 0; off >>= 1)
                sm += __shfl_xor(sm, off);
            float r = ex / sm;
            if (t == ITERS - 1)
                r_out[(size_t)b * (I_SZ * J_SZ) + ii * 64 + jj] = r;
            w_sh[(t + 1) & 1][jj][ii] = p_sh[ii] * r;
        }
        __syncthreads();
    }

    float4 a0 = make_float4(0.f, 0.f, 0.f, 0.f);
    float4 a1 = make_float4(0.f, 0.f, 0.f, 0.f);
#pragma unroll
    for (int i = 0; i < I_SZ; ++i) {
        float wv = w_sh[ITERS & 1][j][i];
        a0.x = fmaf(wv, fw[i][0].x, a0.x); a0.y = fmaf(wv, fw[i][0].y, a0.y);
        a0.z = fmaf(wv, fw[i][0].z, a0.z); a0.w = fmaf(wv, fw[i][0].w, a0.w);
        a1.x = fmaf(wv, fw[i][1].x, a1.x); a1.y = fmaf(wv, fw[i][1].y, a1.y);
        a1.z = fmaf(wv, fw[i][1].z, a1.z); a1.w = fmaf(wv, fw[i][1].w, a1.w);
    }
    float* dst = c_out + (size_t)b * N_SZ + j * E_SZ + sub * 8;
    *(float4*)(dst)     = a0;
    *(float4*)(dst + 4) = a1;
}

extern "C" void kernel_launch(void* const* d_in, const int* in_sizes, int n_in,
                              void* d_out, int out_size, void* d_ws, size_t ws_size,
                              hipStream_t stream) {
    const float* f = (const float*)d_in[0];   // [512,7,512]
    const float* p = (const float*)d_in[1];   // [512,7]
    const float* W = (const float*)d_in[2];   // [7,512,64,128]
    float* out = (float*)d_out;               // c (512*64*128) then r (512*7*64)
    float* fW  = (float*)d_ws;                // 117.4 MB scratch

    vote_gemm_mfma<<<dim3(N_SZ / 256, B_SZ / 128, I_SZ), 256, 0, stream>>>(f, W, fW);
    routing_kernel<<<B_SZ, 1024, 0, stream>>>(fW, p, out, out + (size_t)B_SZ * N_SZ);
}